// Round 1
// baseline (1067.592 us; speedup 1.0000x reference)
//
#include <hip/hip_runtime.h>
#include <hip/hip_bf16.h>

typedef unsigned short u16;
typedef __bf16 bf16x8 __attribute__((ext_vector_type(8)));
typedef float f32x4 __attribute__((ext_vector_type(4)));

#define GLOAD16(gsrc, ldst) \
  __builtin_amdgcn_global_load_lds((const __attribute__((address_space(1))) void*)(gsrc), \
                                   (__attribute__((address_space(3))) void*)(ldst), 16, 0, 0)

__device__ __forceinline__ u16 f2bf(float f) {
  union { float f; unsigned u; } c; c.f = f;
  unsigned r = c.u + 0x7FFFu + ((c.u >> 16) & 1u);
  return (u16)(r >> 16);
}

// ---------------- weight cast / permute / A precompute ----------------
// segments: in_w 4194304 | xp_w 262144 | dt_w 131072 | out_w 2097152 |
//           conv_w permuted (m,f,k)->(m,k,f) 524288 | Apre = -exp(A_log) 65536
__global__ __launch_bounds__(256) void cast_weights_k(
    const float* __restrict__ in_w, const float* __restrict__ xp_w,
    const float* __restrict__ dt_w, const float* __restrict__ out_w,
    const float* __restrict__ conv_w, const float* __restrict__ A_log,
    u16* __restrict__ winb, u16* __restrict__ wxpb, u16* __restrict__ wdtb,
    u16* __restrict__ woutb, u16* __restrict__ wconvb, float* __restrict__ Apre) {
  int i = blockIdx.x * 256 + threadIdx.x;
  if (i < 4194304) { winb[i] = f2bf(in_w[i]); return; }
  i -= 4194304;
  if (i < 262144) { wxpb[i] = f2bf(xp_w[i]); return; }
  i -= 262144;
  if (i < 131072) { wdtb[i] = f2bf(dt_w[i]); return; }
  i -= 131072;
  if (i < 2097152) { woutb[i] = f2bf(out_w[i]); return; }
  i -= 2097152;
  if (i < 524288) {
    const int m = i >> 10, r = i & 1023, kk = r >> 7, ff = r & 127;
    wconvb[i] = f2bf(conv_w[m * 1024 + ff * 8 + kk]);
    return;
  }
  i -= 524288;
  if (i < 65536) Apre[i] = -__expf(A_log[i]);
}

// ---------------- im2col for front conv (kidx = k*128 + f) ----------------
__global__ __launch_bounds__(256) void im2col_k(const float* __restrict__ x,
                                                u16* __restrict__ xc) {
  const int i = blockIdx.x * 256 + threadIdx.x;  // 2048 tokens * 1024 cols
  const int col = i & 1023, tok = i >> 10;
  const int kk = col >> 7, ff = col & 127;
  const int b = tok >> 9, to = tok & 511;
  const int t = to * 4 + kk - 7;
  const float v = (t >= 0) ? x[((size_t)b * 2048 + t) * 128 + ff] : 0.f;
  xc[i] = f2bf(v);
}

// ---------------- bf16 MFMA GEMM: C[M,N] = A[M,K] * Bw[N,K]^T ----------------
// EPI: 0 store f32 | 1 +bias,GELU | 2 store f32 + bf16 dual | 3 +bias,softplus | 4 C += v
template <int WM, int WN, int EPI>
__global__ __launch_bounds__(WM * WN * 64) void gemm_k(
    const u16* __restrict__ A, int lda, const u16* __restrict__ Bw, int ldb,
    float* __restrict__ C, int ldc, int Kd,
    const float* __restrict__ bias, u16* __restrict__ dual) {
  constexpr int BM = WM * 64, BN = WN * 64, NW = WM * WN;
  constexpr int NCH = (BM + BN) / 16;  // 16-row, 1KB LDS chunks
  __shared__ __align__(16) char smem[(BM + BN) * 64];
  const int tid = threadIdx.x;
  const int lane = tid & 63, wid = tid >> 6;
  const int wm = wid % WM, wn = wid / WM;
  const int bm = blockIdx.x, bn = blockIdx.y;
  f32x4 acc[4][4] = {};
  const int srow = lane >> 2, sslot = lane & 3;
  const int nk = Kd >> 5;
  for (int kt = 0; kt < nk; ++kt) {
    // stage A(BMx32) + B(BNx32) via global_load_lds, pre-swizzled source:
    // LDS[row][slot] = G[row][slot ^ ((row>>1)&3)]  (2-way banks on frag read)
    for (int c = wid; c < NCH; c += NW) {
      int lrow, gr, ldx; const u16* src;
      if (c < BM / 16) { lrow = c * 16 + srow; gr = bm * BM + lrow; src = A; ldx = lda; }
      else { lrow = (c - BM / 16) * 16 + srow; gr = bn * BN + lrow; src = Bw; ldx = ldb; }
      const int slot = sslot ^ ((lrow >> 1) & 3);
      GLOAD16(src + (size_t)gr * ldx + kt * 32 + slot * 8, smem + c * 1024);
    }
    __syncthreads();
    const int s = lane >> 4, r0 = lane & 15;
    bf16x8 af[4], bfv[4];
#pragma unroll
    for (int i = 0; i < 4; ++i) {
      const int r = wm * 64 + i * 16 + r0;
      af[i] = *(const bf16x8*)(smem + r * 64 + ((s ^ ((r >> 1) & 3)) << 4));
      const int rn = wn * 64 + i * 16 + r0;
      bfv[i] = *(const bf16x8*)(smem + (BM + rn) * 64 + ((s ^ ((rn >> 1) & 3)) << 4));
    }
#pragma unroll
    for (int mi = 0; mi < 4; ++mi)
#pragma unroll
      for (int ni = 0; ni < 4; ++ni)
        acc[mi][ni] = __builtin_amdgcn_mfma_f32_16x16x32_bf16(af[mi], bfv[ni],
                                                              acc[mi][ni], 0, 0, 0);
    __syncthreads();
  }
  // epilogue: C/D layout col = lane&15, row = (lane>>4)*4 + reg  [m89-verified]
  const int er0 = lane & 15, eg4 = lane >> 4;
#pragma unroll
  for (int mi = 0; mi < 4; ++mi)
#pragma unroll
    for (int ni = 0; ni < 4; ++ni) {
      const int col = bn * BN + wn * 64 + ni * 16 + er0;
#pragma unroll
      for (int r = 0; r < 4; ++r) {
        const int row = bm * BM + wm * 64 + mi * 16 + eg4 * 4 + r;
        float v = acc[mi][ni][r];
        const size_t off = (size_t)row * ldc + col;
        if constexpr (EPI == 0) { C[off] = v; }
        else if constexpr (EPI == 1) {
          v += bias[col];
          C[off] = 0.5f * v * (1.f + erff(v * 0.70710678118f));
        } else if constexpr (EPI == 2) {
          C[off] = v; dual[off] = f2bf(v);
        } else if constexpr (EPI == 3) {
          v += bias[col];
          C[off] = (v > 20.f) ? v : log1pf(__expf(v));
        } else {
          C[off] += v;
        }
      }
    }
}

// ---------------- LayerNorm (DM=512) -> bf16, wave per row ----------------
__global__ __launch_bounds__(256) void ln_bf16_k(const float* __restrict__ h,
                                                 const float* __restrict__ w,
                                                 const float* __restrict__ bb,
                                                 u16* __restrict__ o) {
  const int row = blockIdx.x * 4 + (threadIdx.x >> 6);
  const int lane = threadIdx.x & 63;
  const float* p = h + (size_t)row * 512 + lane * 8;
  float4 a = *(const float4*)p;
  float4 b4 = *(const float4*)(p + 4);
  float v[8] = {a.x, a.y, a.z, a.w, b4.x, b4.y, b4.z, b4.w};
  float s = 0.f, sq = 0.f;
#pragma unroll
  for (int j = 0; j < 8; ++j) { s += v[j]; sq += v[j] * v[j]; }
  for (int off = 32; off; off >>= 1) { s += __shfl_xor(s, off); sq += __shfl_xor(sq, off); }
  const float m = s * (1.f / 512.f);
  const float rs = rsqrtf(sq * (1.f / 512.f) - m * m + 1e-5f);
  const float* wp = w + lane * 8; const float* bp = bb + lane * 8;
  float nv[8];
#pragma unroll
  for (int j = 0; j < 8; ++j) nv[j] = (v[j] - m) * rs * wp[j] + bp[j];
  uint4 uu;
  uu.x = (unsigned)f2bf(nv[0]) | ((unsigned)f2bf(nv[1]) << 16);
  uu.y = (unsigned)f2bf(nv[2]) | ((unsigned)f2bf(nv[3]) << 16);
  uu.z = (unsigned)f2bf(nv[4]) | ((unsigned)f2bf(nv[5]) << 16);
  uu.w = (unsigned)f2bf(nv[6]) | ((unsigned)f2bf(nv[7]) << 16);
  *(uint4*)(o + (size_t)row * 512 + lane * 8) = uu;
}

// ---------------- depthwise causal conv (DC=4) + SiLU ----------------
__global__ __launch_bounds__(256) void dwconv_k(const float* __restrict__ xzp,
                                                const float* __restrict__ cw,
                                                const float* __restrict__ cb,
                                                float* __restrict__ xip,
                                                u16* __restrict__ xib) {
  const int i = blockIdx.x * 256 + threadIdx.x;  // 2048*1024
  const int d = i & 1023, tok = i >> 10, t = tok & 511;
  const float* p = xzp + (size_t)tok * 2048 + d;
  float acc = cb[d];
#pragma unroll
  for (int j = 0; j < 4; ++j) {
    const int ts = t + j - 3;
    if (ts >= 0) acc = fmaf(p[(j - 3) * 2048], cw[d * 4 + j], acc);
  }
  const float v = acc / (1.f + __expf(-acc));
  xip[i] = v;
  xib[i] = f2bf(v);
}

// ---------------- chunked selective scan (16 chunks x 32 steps) ----------------
__global__ __launch_bounds__(256) void scan1_k(const float* __restrict__ dtp,
                                               const float* __restrict__ up,
                                               const float* __restrict__ xd,
                                               const float* __restrict__ Ap,
                                               float* __restrict__ hF,
                                               float* __restrict__ aP) {
  const int blk = blockIdx.x;              // b*64 + c*4 + dblk
  const int d = (blk & 3) * 256 + threadIdx.x;
  const int c = (blk >> 2) & 15, b = blk >> 6;
  float A[16], h[16], ap[16];
#pragma unroll
  for (int n = 0; n < 16; ++n) { A[n] = Ap[d * 16 + n]; h[n] = 0.f; ap[n] = 1.f; }
  const int t0 = c * 32;
  for (int t = t0; t < t0 + 32; ++t) {
    const int tok = b * 512 + t;
    const float dtv = dtp[(size_t)tok * 1024 + d];
    const float u = up[(size_t)tok * 1024 + d];
    const float s = dtv * u;
    const float* Bp = xd + (size_t)tok * 64 + 32;
#pragma unroll
    for (int n = 0; n < 16; ++n) {
      const float dA = __expf(dtv * A[n]);
      h[n] = dA * h[n] + s * Bp[n];
      ap[n] *= dA;
    }
  }
#pragma unroll
  for (int n = 0; n < 16; ++n) {
    const size_t o = ((size_t)(b * 16 + c) * 16 + n) * 1024 + d;
    hF[o] = h[n]; aP[o] = ap[n];
  }
}

__global__ __launch_bounds__(256) void scan2_k(const float* __restrict__ hF,
                                               const float* __restrict__ aP,
                                               float* __restrict__ hI) {
  const int b = blockIdx.x >> 2;
  const int d = (blockIdx.x & 3) * 256 + threadIdx.x;
  float h[16];
#pragma unroll
  for (int n = 0; n < 16; ++n) h[n] = 0.f;
  for (int c = 0; c < 16; ++c) {
#pragma unroll
    for (int n = 0; n < 16; ++n) {
      const size_t o = ((size_t)(b * 16 + c) * 16 + n) * 1024 + d;
      hI[o] = h[n];
      h[n] = aP[o] * h[n] + hF[o];
    }
  }
}

// phase 3: re-scan with correct init, fuse y2 = (y + u*D) * silu(z) -> bf16
__global__ __launch_bounds__(256) void scan3_k(const float* __restrict__ dtp,
                                               const float* __restrict__ up,
                                               const float* __restrict__ xd,
                                               const float* __restrict__ Ap,
                                               const float* __restrict__ hI,
                                               const float* __restrict__ xzp,
                                               const float* __restrict__ Dp,
                                               u16* __restrict__ y2b) {
  const int blk = blockIdx.x;
  const int d = (blk & 3) * 256 + threadIdx.x;
  const int c = (blk >> 2) & 15, b = blk >> 6;
  float A[16], h[16];
#pragma unroll
  for (int n = 0; n < 16; ++n) {
    A[n] = Ap[d * 16 + n];
    h[n] = hI[((size_t)(b * 16 + c) * 16 + n) * 1024 + d];
  }
  const float Dd = Dp[d];
  const int t0 = c * 32;
  for (int t = t0; t < t0 + 32; ++t) {
    const int tok = b * 512 + t;
    const float dtv = dtp[(size_t)tok * 1024 + d];
    const float u = up[(size_t)tok * 1024 + d];
    const float s = dtv * u;
    const float* Bp = xd + (size_t)tok * 64 + 32;
    const float* Cp = xd + (size_t)tok * 64 + 48;
    float y = 0.f;
#pragma unroll
    for (int n = 0; n < 16; ++n) {
      const float dA = __expf(dtv * A[n]);
      h[n] = dA * h[n] + s * Bp[n];
      y = fmaf(h[n], Cp[n], y);
    }
    const float z = xzp[(size_t)tok * 2048 + 1024 + d];
    const float sz = z / (1.f + __expf(-z));
    y2b[(size_t)tok * 1024 + d] = f2bf((y + u * Dd) * sz);
  }
}

// ---------------- final LN + repeat_interleave(4) upsample ----------------
__global__ __launch_bounds__(256) void final_up_k(const float* __restrict__ h,
                                                  const float* __restrict__ w,
                                                  const float* __restrict__ bb,
                                                  float* __restrict__ o) {
  const int row = blockIdx.x * 4 + (threadIdx.x >> 6);  // b*512 + t0
  const int lane = threadIdx.x & 63;
  const float* p = h + (size_t)row * 512 + lane * 8;
  float4 a = *(const float4*)p;
  float4 b4 = *(const float4*)(p + 4);
  float v[8] = {a.x, a.y, a.z, a.w, b4.x, b4.y, b4.z, b4.w};
  float s = 0.f, sq = 0.f;
#pragma unroll
  for (int j = 0; j < 8; ++j) { s += v[j]; sq += v[j] * v[j]; }
  for (int off = 32; off; off >>= 1) { s += __shfl_xor(s, off); sq += __shfl_xor(sq, off); }
  const float m = s * (1.f / 512.f);
  const float rs = rsqrtf(sq * (1.f / 512.f) - m * m + 1e-5f);
  const float* wp = w + lane * 8; const float* bp = bb + lane * 8;
  float nv[8];
#pragma unroll
  for (int j = 0; j < 8; ++j) nv[j] = (v[j] - m) * rs * wp[j] + bp[j];
  const int bi = row >> 9, t0 = row & 511;
  float4 lo; lo.x = nv[0]; lo.y = nv[1]; lo.z = nv[2]; lo.w = nv[3];
  float4 hi; hi.x = nv[4]; hi.y = nv[5]; hi.z = nv[6]; hi.w = nv[7];
  float* ob = o + ((size_t)bi * 2048 + (size_t)t0 * 4) * 512 + lane * 8;
#pragma unroll
  for (int q = 0; q < 4; ++q) {
    *(float4*)(ob + (size_t)q * 512) = lo;
    *(float4*)(ob + (size_t)q * 512 + 4) = hi;
  }
}

extern "C" void kernel_launch(void* const* d_in, const int* in_sizes, int n_in,
                              void* d_out, int out_size, void* d_ws, size_t ws_size,
                              hipStream_t stream) {
  const float* x      = (const float*)d_in[0];
  const float* conv_w = (const float*)d_in[1];
  const float* conv_b = (const float*)d_in[2];
  const float* in_w   = (const float*)d_in[3];
  const float* c1w    = (const float*)d_in[4];
  const float* c1b    = (const float*)d_in[5];
  const float* xp_w   = (const float*)d_in[6];
  const float* dt_w   = (const float*)d_in[7];
  const float* dt_b   = (const float*)d_in[8];
  const float* A_log  = (const float*)d_in[9];
  const float* D_skip = (const float*)d_in[10];
  const float* ln_w   = (const float*)d_in[11];
  const float* ln_b   = (const float*)d_in[12];
  const float* out_w  = (const float*)d_in[13];
  const float* norm_w = (const float*)d_in[14];
  const float* norm_b = (const float*)d_in[15];
  float* out = (float*)d_out;

  float* f = (float*)d_ws;
  float* h    = f; f += 1048576;   // (2048 tok, 512)
  float* xz   = f; f += 4194304;   // (2048, 2048)
  float* xi   = f; f += 2097152;   // (2048, 1024)
  float* xdbl = f; f += 131072;    // (2048, 64)
  float* dtb  = f; f += 2097152;   // (2048, 1024)
  float* Apre = f; f += 65536;     // (4, 1024, 16)
  float* hF   = f; f += 1048576;   // (4,16,16,1024)
  float* aP   = f; f += 1048576;
  float* hI   = f; f += 1048576;
  u16* ub = (u16*)f;
  u16* hnb    = ub; ub += 1048576;
  u16* xib    = ub; ub += 2097152;
  u16* xdblb  = ub; ub += 131072;
  u16* y2b    = ub; ub += 2097152;
  u16* xcolb  = ub; ub += 2097152;
  u16* winb   = ub; ub += 4194304;
  u16* wxpb   = ub; ub += 262144;
  u16* wdtb   = ub; ub += 131072;
  u16* woutb  = ub; ub += 2097152;
  u16* wconvb = ub; ub += 524288;

  cast_weights_k<<<28416, 256, 0, stream>>>(in_w, xp_w, dt_w, out_w, conv_w, A_log,
                                            winb, wxpb, wdtb, woutb, wconvb, Apre);
  im2col_k<<<8192, 256, 0, stream>>>(x, xcolb);
  // front conv as GEMM (M=2048, N=512, K=1024) + bias + exact GELU
  gemm_k<2, 1, 1><<<dim3(16, 8), 128, 0, stream>>>(xcolb, 1024, wconvb, 1024,
                                                   h, 512, 1024, conv_b, nullptr);
  for (int l = 0; l < 4; ++l) {
    ln_bf16_k<<<512, 256, 0, stream>>>(h, ln_w + l * 512, ln_b + l * 512, hnb);
    // in_proj: (2048 x 2048) = hn(2048x512) @ W^T
    gemm_k<2, 2, 0><<<dim3(16, 16), 256, 0, stream>>>(hnb, 512, winb + l * 1048576, 512,
                                                      xz, 2048, 512, nullptr, nullptr);
    dwconv_k<<<8192, 256, 0, stream>>>(xz, c1w + l * 4096, c1b + l * 1024, xi, xib);
    // x_proj: (2048 x 64), dual f32+bf16 store
    gemm_k<2, 1, 2><<<dim3(16, 1), 128, 0, stream>>>(xib, 1024, wxpb + l * 65536, 1024,
                                                     xdbl, 64, 1024, nullptr, xdblb);
    // dt_proj: (2048 x 1024), K=32, A = first 32 cols of xdbl (lda=64), softplus
    gemm_k<2, 2, 3><<<dim3(16, 8), 256, 0, stream>>>(xdblb, 64, wdtb + l * 32768, 32,
                                                     dtb, 1024, 32, dt_b + l * 1024, nullptr);
    scan1_k<<<256, 256, 0, stream>>>(dtb, xi, xdbl, Apre + l * 16384, hF, aP);
    scan2_k<<<16, 256, 0, stream>>>(hF, aP, hI);
    scan3_k<<<256, 256, 0, stream>>>(dtb, xi, xdbl, Apre + l * 16384, hI, xz,
                                     D_skip + l * 1024, y2b);
    // out_proj: (2048 x 512), residual add into h
    gemm_k<2, 1, 4><<<dim3(16, 8), 128, 0, stream>>>(y2b, 1024, woutb + l * 524288, 1024,
                                                     h, 512, 1024, nullptr, nullptr);
  }
  final_up_k<<<512, 256, 0, stream>>>(h, norm_w, norm_b, out);
}

// Round 2
// 722.559 us; speedup vs baseline: 1.4775x; 1.4775x over previous
//
#include <hip/hip_runtime.h>
#include <hip/hip_bf16.h>

typedef unsigned short u16;
typedef __bf16 bf16x8 __attribute__((ext_vector_type(8)));
typedef float f32x4 __attribute__((ext_vector_type(4)));

#define GLOAD16(gsrc, ldst) \
  __builtin_amdgcn_global_load_lds((const __attribute__((address_space(1))) void*)(gsrc), \
                                   (__attribute__((address_space(3))) void*)(ldst), 16, 0, 0)

__device__ __forceinline__ u16 f2bf(float f) {
  union { float f; unsigned u; } c; c.f = f;
  unsigned r = c.u + 0x7FFFu + ((c.u >> 16) & 1u);
  return (u16)(r >> 16);
}

// ---------------- weight cast / permute / A precompute ----------------
// segments: in_w 4194304 | xp_w 262144 | out_w 2097152 | conv_w perm 524288 | Apre 65536
__global__ __launch_bounds__(256) void cast_weights_k(
    const float* __restrict__ in_w, const float* __restrict__ xp_w,
    const float* __restrict__ out_w, const float* __restrict__ conv_w,
    const float* __restrict__ A_log,
    u16* __restrict__ winb, u16* __restrict__ wxpb, u16* __restrict__ woutb,
    u16* __restrict__ wconvb, float* __restrict__ Apre) {
  int i = blockIdx.x * 256 + threadIdx.x;
  if (i < 4194304) { winb[i] = f2bf(in_w[i]); return; }
  i -= 4194304;
  if (i < 262144) { wxpb[i] = f2bf(xp_w[i]); return; }
  i -= 262144;
  if (i < 2097152) { woutb[i] = f2bf(out_w[i]); return; }
  i -= 2097152;
  if (i < 524288) {
    const int m = i >> 10, r = i & 1023, kk = r >> 7, ff = r & 127;
    wconvb[i] = f2bf(conv_w[m * 1024 + ff * 8 + kk]);
    return;
  }
  i -= 524288;
  if (i < 65536) Apre[i] = -__expf(A_log[i]);
}

// ---------------- im2col for front conv (kidx = k*128 + f) ----------------
__global__ __launch_bounds__(256) void im2col_k(const float* __restrict__ x,
                                                u16* __restrict__ xc) {
  const int i = blockIdx.x * 256 + threadIdx.x;  // 2048 tokens * 1024 cols
  const int col = i & 1023, tok = i >> 10;
  const int kk = col >> 7, ff = col & 127;
  const int b = tok >> 9, to = tok & 511;
  const int t = to * 4 + kk - 7;
  const float v = (t >= 0) ? x[((size_t)b * 2048 + t) * 128 + ff] : 0.f;
  xc[i] = f2bf(v);
}

// ---------------- bf16 MFMA GEMM, double-buffered pipeline ----------------
// C[M,N] = A[M,K] * Bw[N,K]^T.  EPI: 0 store f32 | 1 +bias,GELU | 4 C += v
template <int WM, int WN, int EPI>
__global__ __launch_bounds__(WM * WN * 64) void gemm_k(
    const u16* __restrict__ A, int lda, const u16* __restrict__ Bw, int ldb,
    float* __restrict__ C, int ldc, int Kd, const float* __restrict__ bias) {
  constexpr int BM = WM * 64, BN = WN * 64, NW = WM * WN;
  constexpr int NCH = (BM + BN) / 16;  // 16-row, 1KB LDS chunks per K-step
  __shared__ __align__(16) char smem[2 * NCH * 1024];
  const int tid = threadIdx.x;
  const int lane = tid & 63, wid = tid >> 6;
  const int wm = wid % WM, wn = wid / WM;
  const int bm = blockIdx.x, bn = blockIdx.y;
  const int srow = lane >> 2, sslot = lane & 3;
  const int nk = Kd >> 5;
  f32x4 acc[4][4] = {};

  auto stage = [&](int buf, int kt) {
    for (int c = wid; c < NCH; c += NW) {
      int lrow, gr, ldx; const u16* src;
      if (c < BM / 16) { lrow = c * 16 + srow; gr = bm * BM + lrow; src = A; ldx = lda; }
      else { lrow = (c - BM / 16) * 16 + srow; gr = bn * BN + lrow; src = Bw; ldx = ldb; }
      // pre-swizzled source so LDS[row][slot] = G[row][slot ^ ((row>>1)&3)]
      const int slot = sslot ^ ((lrow >> 1) & 3);
      GLOAD16(src + (size_t)gr * ldx + kt * 32 + slot * 8, smem + (buf * NCH + c) * 1024);
    }
  };

  stage(0, 0);
  __syncthreads();  // implicit vmcnt(0): tile 0 staged
  const int s = lane >> 4, r0 = lane & 15;
  for (int kt = 0; kt < nk; ++kt) {
    const int p = kt & 1;
    if (kt + 1 < nk) stage(p ^ 1, kt + 1);  // prefetch overlaps this tile's compute
    bf16x8 af[4], bfv[4];
#pragma unroll
    for (int i = 0; i < 4; ++i) {
      const int r = wm * 64 + i * 16 + r0;
      af[i] = *(const bf16x8*)(smem + p * NCH * 1024 + r * 64 + ((s ^ ((r >> 1) & 3)) << 4));
      const int rn = wn * 64 + i * 16 + r0;
      bfv[i] = *(const bf16x8*)(smem + p * NCH * 1024 + BM * 64 + rn * 64 +
                                ((s ^ ((rn >> 1) & 3)) << 4));
    }
#pragma unroll
    for (int mi = 0; mi < 4; ++mi)
#pragma unroll
      for (int ni = 0; ni < 4; ++ni)
        acc[mi][ni] = __builtin_amdgcn_mfma_f32_16x16x32_bf16(af[mi], bfv[ni],
                                                              acc[mi][ni], 0, 0, 0);
    __syncthreads();  // drains prefetch (vmcnt0) + protects LDS reuse
  }
  // epilogue: C/D layout col = lane&15, row = (lane>>4)*4 + reg
  const int er0 = lane & 15, eg4 = lane >> 4;
#pragma unroll
  for (int mi = 0; mi < 4; ++mi)
#pragma unroll
    for (int ni = 0; ni < 4; ++ni) {
      const int col = bn * BN + wn * 64 + ni * 16 + er0;
#pragma unroll
      for (int r = 0; r < 4; ++r) {
        const int row = bm * BM + wm * 64 + mi * 16 + eg4 * 4 + r;
        float v = acc[mi][ni][r];
        const size_t off = (size_t)row * ldc + col;
        if constexpr (EPI == 0) { C[off] = v; }
        else if constexpr (EPI == 1) {
          v += bias[col];
          C[off] = 0.5f * v * (1.f + erff(v * 0.70710678118f));
        } else {
          C[off] += v;
        }
      }
    }
}

// ---------------- fused dt_proj + softplus (pure VALU) ----------------
// dt[tok,d] = softplus(dot(xdbl[tok,0:32], dtw[d,0:32]) + bias[d])
__global__ __launch_bounds__(256) void dtproj_k(const float* __restrict__ xdbl,
                                                const float* __restrict__ dtw,
                                                const float* __restrict__ dtbias,
                                                float* __restrict__ dtb) {
  __shared__ float xls[32 * 32];
  const int tid = threadIdx.x;
  const int dc = (blockIdx.x & 3) * 256;
  const int tg = (blockIdx.x >> 2) * 32;
  const int d = dc + tid;
  float4 w[8];
#pragma unroll
  for (int j = 0; j < 8; ++j) w[j] = *(const float4*)(dtw + (size_t)d * 32 + j * 4);
  for (int i = tid; i < 1024; i += 256) {
    const int t = i >> 5, r = i & 31;
    xls[i] = xdbl[(size_t)(tg + t) * 64 + r];
  }
  const float b = dtbias[d];
  __syncthreads();
  for (int t = 0; t < 32; ++t) {
    const float4* xr = (const float4*)&xls[t * 32];
    float acc = b;
#pragma unroll
    for (int j = 0; j < 8; ++j) {
      const float4 xv = xr[j];
      acc = fmaf(w[j].x, xv.x, acc); acc = fmaf(w[j].y, xv.y, acc);
      acc = fmaf(w[j].z, xv.z, acc); acc = fmaf(w[j].w, xv.w, acc);
    }
    dtb[(size_t)(tg + t) * 1024 + d] =
        fmaxf(acc, 0.f) + __logf(1.f + __expf(-fabsf(acc)));
  }
}

// ---------------- LayerNorm (DM=512) -> bf16, wave per row ----------------
__global__ __launch_bounds__(256) void ln_bf16_k(const float* __restrict__ h,
                                                 const float* __restrict__ w,
                                                 const float* __restrict__ bb,
                                                 u16* __restrict__ o) {
  const int row = blockIdx.x * 4 + (threadIdx.x >> 6);
  const int lane = threadIdx.x & 63;
  const float* p = h + (size_t)row * 512 + lane * 8;
  float4 a = *(const float4*)p;
  float4 b4 = *(const float4*)(p + 4);
  float v[8] = {a.x, a.y, a.z, a.w, b4.x, b4.y, b4.z, b4.w};
  float s = 0.f, sq = 0.f;
#pragma unroll
  for (int j = 0; j < 8; ++j) { s += v[j]; sq += v[j] * v[j]; }
  for (int off = 32; off; off >>= 1) { s += __shfl_xor(s, off); sq += __shfl_xor(sq, off); }
  const float m = s * (1.f / 512.f);
  const float rs = rsqrtf(sq * (1.f / 512.f) - m * m + 1e-5f);
  const float* wp = w + lane * 8; const float* bp = bb + lane * 8;
  float nv[8];
#pragma unroll
  for (int j = 0; j < 8; ++j) nv[j] = (v[j] - m) * rs * wp[j] + bp[j];
  uint4 uu;
  uu.x = (unsigned)f2bf(nv[0]) | ((unsigned)f2bf(nv[1]) << 16);
  uu.y = (unsigned)f2bf(nv[2]) | ((unsigned)f2bf(nv[3]) << 16);
  uu.z = (unsigned)f2bf(nv[4]) | ((unsigned)f2bf(nv[5]) << 16);
  uu.w = (unsigned)f2bf(nv[6]) | ((unsigned)f2bf(nv[7]) << 16);
  *(uint4*)(o + (size_t)row * 512 + lane * 8) = uu;
}

// ---------------- depthwise causal conv (DC=4) + SiLU ----------------
__global__ __launch_bounds__(256) void dwconv_k(const float* __restrict__ xzp,
                                                const float* __restrict__ cw,
                                                const float* __restrict__ cb,
                                                float* __restrict__ xip,
                                                u16* __restrict__ xib) {
  const int i = blockIdx.x * 256 + threadIdx.x;  // 2048*1024
  const int d = i & 1023, tok = i >> 10, t = tok & 511;
  const float* p = xzp + (size_t)tok * 2048 + d;
  float acc = cb[d];
#pragma unroll
  for (int j = 0; j < 4; ++j) {
    const int ts = t + j - 3;
    if (ts >= 0) acc = fmaf(p[(j - 3) * 2048], cw[d * 4 + j], acc);
  }
  const float v = acc / (1.f + __expf(-acc));
  xip[i] = v;
  xib[i] = f2bf(v);
}

// ---------------- chunked selective scan (16 chunks x 32 steps) ----------------
__global__ __launch_bounds__(256) void scan1_k(const float* __restrict__ dtp,
                                               const float* __restrict__ up,
                                               const float* __restrict__ xd,
                                               const float* __restrict__ Ap,
                                               float* __restrict__ hF,
                                               float* __restrict__ aP) {
  const int blk = blockIdx.x;              // b*64 + c*4 + dblk
  const int d = (blk & 3) * 256 + threadIdx.x;
  const int c = (blk >> 2) & 15, b = blk >> 6;
  float A[16], h[16], ap[16];
#pragma unroll
  for (int n = 0; n < 16; ++n) { A[n] = Ap[d * 16 + n]; h[n] = 0.f; ap[n] = 1.f; }
  const int t0 = c * 32;
  for (int t = t0; t < t0 + 32; ++t) {
    const int tok = b * 512 + t;
    const float dtv = dtp[(size_t)tok * 1024 + d];
    const float u = up[(size_t)tok * 1024 + d];
    const float s = dtv * u;
    const float* Bp = xd + (size_t)tok * 64 + 32;
#pragma unroll
    for (int n = 0; n < 16; ++n) {
      const float dA = __expf(dtv * A[n]);
      h[n] = dA * h[n] + s * Bp[n];
      ap[n] *= dA;
    }
  }
#pragma unroll
  for (int n = 0; n < 16; ++n) {
    const size_t o = ((size_t)(b * 16 + c) * 16 + n) * 1024 + d;
    hF[o] = h[n]; aP[o] = ap[n];
  }
}

__global__ __launch_bounds__(256) void scan2_k(const float* __restrict__ hF,
                                               const float* __restrict__ aP,
                                               float* __restrict__ hI) {
  // block: b(4) x n(16) x dblk(4); thread: d  -> 256 blocks
  const int bi = blockIdx.x >> 6;
  const int n = (blockIdx.x >> 2) & 15;
  const int d = (blockIdx.x & 3) * 256 + threadIdx.x;
  float h = 0.f;
  for (int c = 0; c < 16; ++c) {
    const size_t o = ((size_t)((bi * 16 + c) * 16 + n)) * 1024 + d;
    hI[o] = h;
    h = fmaf(aP[o], h, hF[o]);
  }
}

// phase 3: re-scan with correct init, fuse y2 = (y + u*D) * silu(z) -> bf16
__global__ __launch_bounds__(256) void scan3_k(const float* __restrict__ dtp,
                                               const float* __restrict__ up,
                                               const float* __restrict__ xd,
                                               const float* __restrict__ Ap,
                                               const float* __restrict__ hI,
                                               const float* __restrict__ xzp,
                                               const float* __restrict__ Dp,
                                               u16* __restrict__ y2b) {
  const int blk = blockIdx.x;
  const int d = (blk & 3) * 256 + threadIdx.x;
  const int c = (blk >> 2) & 15, b = blk >> 6;
  float A[16], h[16];
#pragma unroll
  for (int n = 0; n < 16; ++n) {
    A[n] = Ap[d * 16 + n];
    h[n] = hI[((size_t)(b * 16 + c) * 16 + n) * 1024 + d];
  }
  const float Dd = Dp[d];
  const int t0 = c * 32;
  for (int t = t0; t < t0 + 32; ++t) {
    const int tok = b * 512 + t;
    const float dtv = dtp[(size_t)tok * 1024 + d];
    const float u = up[(size_t)tok * 1024 + d];
    const float s = dtv * u;
    const float* Bp = xd + (size_t)tok * 64 + 32;
    const float* Cp = xd + (size_t)tok * 64 + 48;
    float y = 0.f;
#pragma unroll
    for (int n = 0; n < 16; ++n) {
      const float dA = __expf(dtv * A[n]);
      h[n] = dA * h[n] + s * Bp[n];
      y = fmaf(h[n], Cp[n], y);
    }
    const float z = xzp[(size_t)tok * 2048 + 1024 + d];
    const float sz = z / (1.f + __expf(-z));
    y2b[(size_t)tok * 1024 + d] = f2bf((y + u * Dd) * sz);
  }
}

// ---------------- final LN + repeat_interleave(4) upsample ----------------
__global__ __launch_bounds__(256) void final_up_k(const float* __restrict__ h,
                                                  const float* __restrict__ w,
                                                  const float* __restrict__ bb,
                                                  float* __restrict__ o) {
  const int row = blockIdx.x * 4 + (threadIdx.x >> 6);  // b*512 + t0
  const int lane = threadIdx.x & 63;
  const float* p = h + (size_t)row * 512 + lane * 8;
  float4 a = *(const float4*)p;
  float4 b4 = *(const float4*)(p + 4);
  float v[8] = {a.x, a.y, a.z, a.w, b4.x, b4.y, b4.z, b4.w};
  float s = 0.f, sq = 0.f;
#pragma unroll
  for (int j = 0; j < 8; ++j) { s += v[j]; sq += v[j] * v[j]; }
  for (int off = 32; off; off >>= 1) { s += __shfl_xor(s, off); sq += __shfl_xor(sq, off); }
  const float m = s * (1.f / 512.f);
  const float rs = rsqrtf(sq * (1.f / 512.f) - m * m + 1e-5f);
  const float* wp = w + lane * 8; const float* bp = bb + lane * 8;
  float nv[8];
#pragma unroll
  for (int j = 0; j < 8; ++j) nv[j] = (v[j] - m) * rs * wp[j] + bp[j];
  const int bi = row >> 9, t0 = row & 511;
  float4 lo; lo.x = nv[0]; lo.y = nv[1]; lo.z = nv[2]; lo.w = nv[3];
  float4 hi; hi.x = nv[4]; hi.y = nv[5]; hi.z = nv[6]; hi.w = nv[7];
  float* ob = o + ((size_t)bi * 2048 + (size_t)t0 * 4) * 512 + lane * 8;
#pragma unroll
  for (int q = 0; q < 4; ++q) {
    *(float4*)(ob + (size_t)q * 512) = lo;
    *(float4*)(ob + (size_t)q * 512 + 4) = hi;
  }
}

extern "C" void kernel_launch(void* const* d_in, const int* in_sizes, int n_in,
                              void* d_out, int out_size, void* d_ws, size_t ws_size,
                              hipStream_t stream) {
  const float* x      = (const float*)d_in[0];
  const float* conv_w = (const float*)d_in[1];
  const float* conv_b = (const float*)d_in[2];
  const float* in_w   = (const float*)d_in[3];
  const float* c1w    = (const float*)d_in[4];
  const float* c1b    = (const float*)d_in[5];
  const float* xp_w   = (const float*)d_in[6];
  const float* dt_w   = (const float*)d_in[7];
  const float* dt_b   = (const float*)d_in[8];
  const float* A_log  = (const float*)d_in[9];
  const float* D_skip = (const float*)d_in[10];
  const float* ln_w   = (const float*)d_in[11];
  const float* ln_b   = (const float*)d_in[12];
  const float* out_w  = (const float*)d_in[13];
  const float* norm_w = (const float*)d_in[14];
  const float* norm_b = (const float*)d_in[15];
  float* out = (float*)d_out;

  float* f = (float*)d_ws;
  float* h    = f; f += 1048576;   // (2048 tok, 512)
  float* xz   = f; f += 4194304;   // (2048, 2048)
  float* xi   = f; f += 2097152;   // (2048, 1024)
  float* xdbl = f; f += 131072;    // (2048, 64)
  float* dtb  = f; f += 2097152;   // (2048, 1024)
  float* Apre = f; f += 65536;     // (4, 1024, 16)
  float* hF   = f; f += 1048576;   // (4,16,16,1024)
  float* aP   = f; f += 1048576;
  float* hI   = f; f += 1048576;
  u16* ub = (u16*)f;
  u16* hnb    = ub; ub += 1048576;
  u16* xib    = ub; ub += 2097152;
  u16* y2b    = ub; ub += 2097152;
  u16* xcolb  = ub; ub += 2097152;
  u16* winb   = ub; ub += 4194304;
  u16* wxpb   = ub; ub += 262144;
  u16* woutb  = ub; ub += 2097152;
  u16* wconvb = ub; ub += 524288;

  cast_weights_k<<<27904, 256, 0, stream>>>(in_w, xp_w, out_w, conv_w, A_log,
                                            winb, wxpb, woutb, wconvb, Apre);
  im2col_k<<<8192, 256, 0, stream>>>(x, xcolb);
  // front conv as GEMM (M=2048, N=512, K=1024) + bias + exact GELU
  gemm_k<1, 1, 1><<<dim3(32, 8), 64, 0, stream>>>(xcolb, 1024, wconvb, 1024,
                                                  h, 512, 1024, conv_b);
  for (int l = 0; l < 4; ++l) {
    ln_bf16_k<<<512, 256, 0, stream>>>(h, ln_w + l * 512, ln_b + l * 512, hnb);
    // in_proj: (2048 x 2048), 64x128 tiles -> 512 blocks x 2 waves
    gemm_k<1, 2, 0><<<dim3(32, 16), 128, 0, stream>>>(hnb, 512, winb + l * 1048576, 512,
                                                      xz, 2048, 512, nullptr);
    dwconv_k<<<8192, 256, 0, stream>>>(xz, c1w + l * 4096, c1b + l * 1024, xi, xib);
    // x_proj: (2048 x 64)
    gemm_k<1, 1, 0><<<dim3(32, 1), 64, 0, stream>>>(xib, 1024, wxpb + l * 65536,
                                                    1024, xdbl, 64, 1024, nullptr);
    // dt_proj fused VALU kernel (K=32) + softplus
    dtproj_k<<<256, 256, 0, stream>>>(xdbl, dt_w + l * 32768, dt_b + l * 1024, dtb);
    scan1_k<<<256, 256, 0, stream>>>(dtb, xi, xdbl, Apre + l * 16384, hF, aP);
    scan2_k<<<256, 256, 0, stream>>>(hF, aP, hI);
    scan3_k<<<256, 256, 0, stream>>>(dtb, xi, xdbl, Apre + l * 16384, hI, xz,
                                     D_skip + l * 1024, y2b);
    // out_proj: (2048 x 512), residual add into h
    gemm_k<1, 1, 4><<<dim3(32, 8), 64, 0, stream>>>(y2b, 1024, woutb + l * 524288,
                                                    1024, h, 512, 1024, nullptr);
  }
  final_up_k<<<512, 256, 0, stream>>>(h, norm_w, norm_b, out);
}

// Round 3
// 512.549 us; speedup vs baseline: 2.0829x; 1.4097x over previous
//
#include <hip/hip_runtime.h>
#include <hip/hip_bf16.h>

typedef unsigned short u16;
typedef __bf16 bf16x8 __attribute__((ext_vector_type(8)));
typedef float f32x4 __attribute__((ext_vector_type(4)));

#define GLOAD16(gsrc, ldst) \
  __builtin_amdgcn_global_load_lds((const __attribute__((address_space(1))) void*)(gsrc), \
                                   (__attribute__((address_space(3))) void*)(ldst), 16, 0, 0)

__device__ __forceinline__ u16 f2bf(float f) {
  union { float f; unsigned u; } c; c.f = f;
  unsigned r = c.u + 0x7FFFu + ((c.u >> 16) & 1u);
  return (u16)(r >> 16);
}

// ---------------- weight cast / permute / A precompute ----------------
__global__ __launch_bounds__(256) void cast_weights_k(
    const float* __restrict__ in_w, const float* __restrict__ xp_w,
    const float* __restrict__ out_w, const float* __restrict__ conv_w,
    const float* __restrict__ A_log,
    u16* __restrict__ winb, u16* __restrict__ wxpb, u16* __restrict__ woutb,
    u16* __restrict__ wconvb, float* __restrict__ Apre) {
  int i = blockIdx.x * 256 + threadIdx.x;
  if (i < 4194304) { winb[i] = f2bf(in_w[i]); return; }
  i -= 4194304;
  if (i < 262144) { wxpb[i] = f2bf(xp_w[i]); return; }
  i -= 262144;
  if (i < 2097152) { woutb[i] = f2bf(out_w[i]); return; }
  i -= 2097152;
  if (i < 524288) {
    const int m = i >> 10, r = i & 1023, kk = r >> 7, ff = r & 127;
    wconvb[i] = f2bf(conv_w[m * 1024 + ff * 8 + kk]);
    return;
  }
  i -= 524288;
  if (i < 65536) Apre[i] = -__expf(A_log[i]);
}

// ---------------- im2col for front conv (kidx = k*128 + f) ----------------
__global__ __launch_bounds__(256) void im2col_k(const float* __restrict__ x,
                                                u16* __restrict__ xc) {
  const int i = blockIdx.x * 256 + threadIdx.x;  // 2048 tokens * 1024 cols
  const int col = i & 1023, tok = i >> 10;
  const int kk = col >> 7, ff = col & 127;
  const int b = tok >> 9, to = tok & 511;
  const int t = to * 4 + kk - 7;
  const float v = (t >= 0) ? x[((size_t)b * 2048 + t) * 128 + ff] : 0.f;
  xc[i] = f2bf(v);
}

// ---------------- 1-wave 64x64 MFMA GEMM, quad-buffer, counted-vmcnt ----------------
// C[M,N] = A[M,K] * Bw[N,K]^T.  EPI: 0 store f32 | 1 +bias,GELU | 4 C += v
// Single wave per block => no __syncthreads needed; deep pipeline with
// s_waitcnt vmcnt(N) keeps 2 stage-groups (16 loads) in flight across steps.
template <int EPI>
__global__ __launch_bounds__(64) void gemm_k(
    const u16* __restrict__ A, int lda, const u16* __restrict__ Bw, int ldb,
    float* __restrict__ C, int ldc, int Kd, const float* __restrict__ bias) {
  __shared__ __align__(16) char smem[4 * 8192];  // 4 bufs x (A 4KB + B 4KB)
  const int lane = threadIdx.x;
  const int bm = blockIdx.x, bn = blockIdx.y;
  const int srow = lane >> 2, sslot = lane & 3;
  const int nk = Kd >> 5;
  f32x4 acc[4][4] = {};

  auto stage = [&](int buf, int kt) {
#pragma unroll
    for (int c = 0; c < 8; ++c) {
      int lrow, gr, ldx; const u16* src;
      if (c < 4) { lrow = c * 16 + srow; gr = bm * 64 + lrow; src = A; ldx = lda; }
      else { lrow = (c - 4) * 16 + srow; gr = bn * 64 + lrow; src = Bw; ldx = ldb; }
      // pre-swizzled source so LDS[row][slot] = G[row][slot ^ ((row>>1)&3)]
      const int slot = sslot ^ ((lrow >> 1) & 3);
      GLOAD16(src + (size_t)gr * ldx + kt * 32 + slot * 8, smem + buf * 8192 + c * 1024);
    }
  };

  stage(0, 0);
  stage(1, 1);
  stage(2, 2);
  const int s = lane >> 4, r0 = lane & 15;
  for (int kt = 0; kt < nk; ++kt) {
    const int p = kt & 3;
    // wait until tile kt's 8 loads have landed; keep later stages in flight
    if (kt + 2 < nk)      asm volatile("s_waitcnt vmcnt(16)" ::: "memory");
    else if (kt + 1 < nk) asm volatile("s_waitcnt vmcnt(8)" ::: "memory");
    else                  asm volatile("s_waitcnt vmcnt(0)" ::: "memory");
    __builtin_amdgcn_sched_barrier(0);
    bf16x8 af[4], bfv[4];
#pragma unroll
    for (int i = 0; i < 4; ++i) {
      const int r = i * 16 + r0;
      af[i] = *(const bf16x8*)(smem + p * 8192 + r * 64 + ((s ^ ((r >> 1) & 3)) << 4));
      bfv[i] = *(const bf16x8*)(smem + p * 8192 + 4096 + r * 64 + ((s ^ ((r >> 1) & 3)) << 4));
    }
#pragma unroll
    for (int mi = 0; mi < 4; ++mi)
#pragma unroll
      for (int ni = 0; ni < 4; ++ni)
        acc[mi][ni] = __builtin_amdgcn_mfma_f32_16x16x32_bf16(af[mi], bfv[ni],
                                                              acc[mi][ni], 0, 0, 0);
    // pin: all ds_reads above retired (lgkm waits precede last MFMA), so the
    // next stage's LDS writes can't race the reads of this (or older) tiles.
    __builtin_amdgcn_sched_barrier(0);
    if (kt + 3 < nk) stage((kt + 3) & 3, kt + 3);
  }
  // epilogue: C/D layout col = lane&15, row = (lane>>4)*4 + reg
  const int er0 = lane & 15, eg4 = lane >> 4;
#pragma unroll
  for (int mi = 0; mi < 4; ++mi)
#pragma unroll
    for (int ni = 0; ni < 4; ++ni) {
      const int col = bn * 64 + ni * 16 + er0;
#pragma unroll
      for (int r = 0; r < 4; ++r) {
        const int row = bm * 64 + mi * 16 + eg4 * 4 + r;
        float v = acc[mi][ni][r];
        const size_t off = (size_t)row * ldc + col;
        if constexpr (EPI == 0) { C[off] = v; }
        else if constexpr (EPI == 1) {
          v += bias[col];
          C[off] = 0.5f * v * (1.f + erff(v * 0.70710678118f));
        } else {
          C[off] += v;
        }
      }
    }
}

// ---------------- fused dt_proj + softplus (pure VALU) ----------------
__global__ __launch_bounds__(256) void dtproj_k(const float* __restrict__ xdbl,
                                                const float* __restrict__ dtw,
                                                const float* __restrict__ dtbias,
                                                float* __restrict__ dtb) {
  __shared__ float xls[32 * 32];
  const int tid = threadIdx.x;
  const int dc = (blockIdx.x & 3) * 256;
  const int tg = (blockIdx.x >> 2) * 32;
  const int d = dc + tid;
  float4 w[8];
#pragma unroll
  for (int j = 0; j < 8; ++j) w[j] = *(const float4*)(dtw + (size_t)d * 32 + j * 4);
  for (int i = tid; i < 1024; i += 256) {
    const int t = i >> 5, r = i & 31;
    xls[i] = xdbl[(size_t)(tg + t) * 64 + r];
  }
  const float b = dtbias[d];
  __syncthreads();
  for (int t = 0; t < 32; ++t) {
    const float4* xr = (const float4*)&xls[t * 32];
    float acc = b;
#pragma unroll
    for (int j = 0; j < 8; ++j) {
      const float4 xv = xr[j];
      acc = fmaf(w[j].x, xv.x, acc); acc = fmaf(w[j].y, xv.y, acc);
      acc = fmaf(w[j].z, xv.z, acc); acc = fmaf(w[j].w, xv.w, acc);
    }
    dtb[(size_t)(tg + t) * 1024 + d] =
        fmaxf(acc, 0.f) + __logf(1.f + __expf(-fabsf(acc)));
  }
}

// ---------------- LayerNorm (DM=512) -> bf16, wave per row ----------------
__global__ __launch_bounds__(256) void ln_bf16_k(const float* __restrict__ h,
                                                 const float* __restrict__ w,
                                                 const float* __restrict__ bb,
                                                 u16* __restrict__ o) {
  const int row = blockIdx.x * 4 + (threadIdx.x >> 6);
  const int lane = threadIdx.x & 63;
  const float* p = h + (size_t)row * 512 + lane * 8;
  float4 a = *(const float4*)p;
  float4 b4 = *(const float4*)(p + 4);
  float v[8] = {a.x, a.y, a.z, a.w, b4.x, b4.y, b4.z, b4.w};
  float s = 0.f, sq = 0.f;
#pragma unroll
  for (int j = 0; j < 8; ++j) { s += v[j]; sq += v[j] * v[j]; }
  for (int off = 32; off; off >>= 1) { s += __shfl_xor(s, off); sq += __shfl_xor(sq, off); }
  const float m = s * (1.f / 512.f);
  const float rs = rsqrtf(sq * (1.f / 512.f) - m * m + 1e-5f);
  const float* wp = w + lane * 8; const float* bp = bb + lane * 8;
  float nv[8];
#pragma unroll
  for (int j = 0; j < 8; ++j) nv[j] = (v[j] - m) * rs * wp[j] + bp[j];
  uint4 uu;
  uu.x = (unsigned)f2bf(nv[0]) | ((unsigned)f2bf(nv[1]) << 16);
  uu.y = (unsigned)f2bf(nv[2]) | ((unsigned)f2bf(nv[3]) << 16);
  uu.z = (unsigned)f2bf(nv[4]) | ((unsigned)f2bf(nv[5]) << 16);
  uu.w = (unsigned)f2bf(nv[6]) | ((unsigned)f2bf(nv[7]) << 16);
  *(uint4*)(o + (size_t)row * 512 + lane * 8) = uu;
}

// ---------------- depthwise causal conv (DC=4) + SiLU ----------------
__global__ __launch_bounds__(256) void dwconv_k(const float* __restrict__ xzp,
                                                const float* __restrict__ cw,
                                                const float* __restrict__ cb,
                                                float* __restrict__ xip,
                                                u16* __restrict__ xib) {
  const int i = blockIdx.x * 256 + threadIdx.x;  // 2048*1024
  const int d = i & 1023, tok = i >> 10, t = tok & 511;
  const float* p = xzp + (size_t)tok * 2048 + d;
  float acc = cb[d];
#pragma unroll
  for (int j = 0; j < 4; ++j) {
    const int ts = t + j - 3;
    if (ts >= 0) acc = fmaf(p[(j - 3) * 2048], cw[d * 4 + j], acc);
  }
  const float v = acc / (1.f + __expf(-acc));
  xip[i] = v;
  xib[i] = f2bf(v);
}

// ---------------- chunked selective scan (16 chunks x 32 steps) ----------------
__global__ __launch_bounds__(256) void scan1_k(const float* __restrict__ dtp,
                                               const float* __restrict__ up,
                                               const float* __restrict__ xd,
                                               const float* __restrict__ Ap,
                                               float* __restrict__ hF,
                                               float* __restrict__ aP) {
  const int blk = blockIdx.x;              // b*64 + c*4 + dblk
  const int d = (blk & 3) * 256 + threadIdx.x;
  const int c = (blk >> 2) & 15, b = blk >> 6;
  float A[16], h[16], ap[16];
#pragma unroll
  for (int n = 0; n < 16; ++n) { A[n] = Ap[d * 16 + n]; h[n] = 0.f; ap[n] = 1.f; }
  const int t0 = c * 32;
  for (int t = t0; t < t0 + 32; ++t) {
    const int tok = b * 512 + t;
    const float dtv = dtp[(size_t)tok * 1024 + d];
    const float u = up[(size_t)tok * 1024 + d];
    const float s = dtv * u;
    const float* Bp = xd + (size_t)tok * 64 + 32;
#pragma unroll
    for (int n = 0; n < 16; ++n) {
      const float dA = __expf(dtv * A[n]);
      h[n] = dA * h[n] + s * Bp[n];
      ap[n] *= dA;
    }
  }
#pragma unroll
  for (int n = 0; n < 16; ++n) {
    const size_t o = ((size_t)(b * 16 + c) * 16 + n) * 1024 + d;
    hF[o] = h[n]; aP[o] = ap[n];
  }
}

__global__ __launch_bounds__(256) void scan2_k(const float* __restrict__ hF,
                                               const float* __restrict__ aP,
                                               float* __restrict__ hI) {
  // block: b(4) x n(16) x dblk(4); thread: d  -> 256 blocks
  const int bi = blockIdx.x >> 6;
  const int n = (blockIdx.x >> 2) & 15;
  const int d = (blockIdx.x & 3) * 256 + threadIdx.x;
  float h = 0.f;
  for (int c = 0; c < 16; ++c) {
    const size_t o = ((size_t)((bi * 16 + c) * 16 + n)) * 1024 + d;
    hI[o] = h;
    h = fmaf(aP[o], h, hF[o]);
  }
}

// phase 3: re-scan with correct init, fuse y2 = (y + u*D) * silu(z) -> bf16
__global__ __launch_bounds__(256) void scan3_k(const float* __restrict__ dtp,
                                               const float* __restrict__ up,
                                               const float* __restrict__ xd,
                                               const float* __restrict__ Ap,
                                               const float* __restrict__ hI,
                                               const float* __restrict__ xzp,
                                               const float* __restrict__ Dp,
                                               u16* __restrict__ y2b) {
  const int blk = blockIdx.x;
  const int d = (blk & 3) * 256 + threadIdx.x;
  const int c = (blk >> 2) & 15, b = blk >> 6;
  float A[16], h[16];
#pragma unroll
  for (int n = 0; n < 16; ++n) {
    A[n] = Ap[d * 16 + n];
    h[n] = hI[((size_t)(b * 16 + c) * 16 + n) * 1024 + d];
  }
  const float Dd = Dp[d];
  const int t0 = c * 32;
  for (int t = t0; t < t0 + 32; ++t) {
    const int tok = b * 512 + t;
    const float dtv = dtp[(size_t)tok * 1024 + d];
    const float u = up[(size_t)tok * 1024 + d];
    const float s = dtv * u;
    const float* Bp = xd + (size_t)tok * 64 + 32;
    const float* Cp = xd + (size_t)tok * 64 + 48;
    float y = 0.f;
#pragma unroll
    for (int n = 0; n < 16; ++n) {
      const float dA = __expf(dtv * A[n]);
      h[n] = dA * h[n] + s * Bp[n];
      y = fmaf(h[n], Cp[n], y);
    }
    const float z = xzp[(size_t)tok * 2048 + 1024 + d];
    const float sz = z / (1.f + __expf(-z));
    y2b[(size_t)tok * 1024 + d] = f2bf((y + u * Dd) * sz);
  }
}

// ---------------- final LN + repeat_interleave(4) upsample ----------------
__global__ __launch_bounds__(256) void final_up_k(const float* __restrict__ h,
                                                  const float* __restrict__ w,
                                                  const float* __restrict__ bb,
                                                  float* __restrict__ o) {
  const int row = blockIdx.x * 4 + (threadIdx.x >> 6);  // b*512 + t0
  const int lane = threadIdx.x & 63;
  const float* p = h + (size_t)row * 512 + lane * 8;
  float4 a = *(const float4*)p;
  float4 b4 = *(const float4*)(p + 4);
  float v[8] = {a.x, a.y, a.z, a.w, b4.x, b4.y, b4.z, b4.w};
  float s = 0.f, sq = 0.f;
#pragma unroll
  for (int j = 0; j < 8; ++j) { s += v[j]; sq += v[j] * v[j]; }
  for (int off = 32; off; off >>= 1) { s += __shfl_xor(s, off); sq += __shfl_xor(sq, off); }
  const float m = s * (1.f / 512.f);
  const float rs = rsqrtf(sq * (1.f / 512.f) - m * m + 1e-5f);
  const float* wp = w + lane * 8; const float* bp = bb + lane * 8;
  float nv[8];
#pragma unroll
  for (int j = 0; j < 8; ++j) nv[j] = (v[j] - m) * rs * wp[j] + bp[j];
  const int bi = row >> 9, t0 = row & 511;
  float4 lo; lo.x = nv[0]; lo.y = nv[1]; lo.z = nv[2]; lo.w = nv[3];
  float4 hi; hi.x = nv[4]; hi.y = nv[5]; hi.z = nv[6]; hi.w = nv[7];
  float* ob = o + ((size_t)bi * 2048 + (size_t)t0 * 4) * 512 + lane * 8;
#pragma unroll
  for (int q = 0; q < 4; ++q) {
    *(float4*)(ob + (size_t)q * 512) = lo;
    *(float4*)(ob + (size_t)q * 512 + 4) = hi;
  }
}

extern "C" void kernel_launch(void* const* d_in, const int* in_sizes, int n_in,
                              void* d_out, int out_size, void* d_ws, size_t ws_size,
                              hipStream_t stream) {
  const float* x      = (const float*)d_in[0];
  const float* conv_w = (const float*)d_in[1];
  const float* conv_b = (const float*)d_in[2];
  const float* in_w   = (const float*)d_in[3];
  const float* c1w    = (const float*)d_in[4];
  const float* c1b    = (const float*)d_in[5];
  const float* xp_w   = (const float*)d_in[6];
  const float* dt_w   = (const float*)d_in[7];
  const float* dt_b   = (const float*)d_in[8];
  const float* A_log  = (const float*)d_in[9];
  const float* D_skip = (const float*)d_in[10];
  const float* ln_w   = (const float*)d_in[11];
  const float* ln_b   = (const float*)d_in[12];
  const float* out_w  = (const float*)d_in[13];
  const float* norm_w = (const float*)d_in[14];
  const float* norm_b = (const float*)d_in[15];
  float* out = (float*)d_out;

  float* f = (float*)d_ws;
  float* h    = f; f += 1048576;   // (2048 tok, 512)
  float* xz   = f; f += 4194304;   // (2048, 2048)
  float* xi   = f; f += 2097152;   // (2048, 1024)
  float* xdbl = f; f += 131072;    // (2048, 64)
  float* dtb  = f; f += 2097152;   // (2048, 1024)
  float* Apre = f; f += 65536;     // (4, 1024, 16)
  float* hF   = f; f += 1048576;   // (4,16,16,1024)
  float* aP   = f; f += 1048576;
  float* hI   = f; f += 1048576;
  u16* ub = (u16*)f;
  u16* hnb    = ub; ub += 1048576;
  u16* xib    = ub; ub += 2097152;
  u16* y2b    = ub; ub += 2097152;
  u16* xcolb  = ub; ub += 2097152;
  u16* winb   = ub; ub += 4194304;
  u16* wxpb   = ub; ub += 262144;
  u16* woutb  = ub; ub += 2097152;
  u16* wconvb = ub; ub += 524288;

  cast_weights_k<<<27904, 256, 0, stream>>>(in_w, xp_w, out_w, conv_w, A_log,
                                            winb, wxpb, woutb, wconvb, Apre);
  im2col_k<<<8192, 256, 0, stream>>>(x, xcolb);
  // front conv as GEMM (M=2048, N=512, K=1024) + bias + exact GELU
  gemm_k<1><<<dim3(32, 8), 64, 0, stream>>>(xcolb, 1024, wconvb, 1024,
                                            h, 512, 1024, conv_b);
  for (int l = 0; l < 4; ++l) {
    ln_bf16_k<<<512, 256, 0, stream>>>(h, ln_w + l * 512, ln_b + l * 512, hnb);
    // in_proj: (2048 x 2048), 64x64 1-wave tiles -> 1024 blocks (4/CU TLP)
    gemm_k<0><<<dim3(32, 32), 64, 0, stream>>>(hnb, 512, winb + l * 1048576, 512,
                                               xz, 2048, 512, nullptr);
    dwconv_k<<<8192, 256, 0, stream>>>(xz, c1w + l * 4096, c1b + l * 1024, xi, xib);
    // x_proj: (2048 x 64)
    gemm_k<0><<<dim3(32, 1), 64, 0, stream>>>(xib, 1024, wxpb + l * 65536,
                                              1024, xdbl, 64, 1024, nullptr);
    // dt_proj fused VALU kernel (K=32) + softplus
    dtproj_k<<<256, 256, 0, stream>>>(xdbl, dt_w + l * 32768, dt_b + l * 1024, dtb);
    scan1_k<<<256, 256, 0, stream>>>(dtb, xi, xdbl, Apre + l * 16384, hF, aP);
    scan2_k<<<256, 256, 0, stream>>>(hF, aP, hI);
    scan3_k<<<256, 256, 0, stream>>>(dtb, xi, xdbl, Apre + l * 16384, hI, xz,
                                     D_skip + l * 1024, y2b);
    // out_proj: (2048 x 512), residual add into h
    gemm_k<4><<<dim3(32, 8), 64, 0, stream>>>(y2b, 1024, woutb + l * 524288,
                                              1024, h, 512, 1024, nullptr);
  }
  final_up_k<<<512, 256, 0, stream>>>(h, norm_w, norm_b, out);
}

// Round 4
// 439.742 us; speedup vs baseline: 2.4278x; 1.1656x over previous
//
#include <hip/hip_runtime.h>
#include <hip/hip_bf16.h>

typedef unsigned short u16;
typedef __bf16 bf16x8 __attribute__((ext_vector_type(8)));
typedef float f32x4 __attribute__((ext_vector_type(4)));

#define GLOAD16(gsrc, ldst) \
  __builtin_amdgcn_global_load_lds((const __attribute__((address_space(1))) void*)(gsrc), \
                                   (__attribute__((address_space(3))) void*)(ldst), 16, 0, 0)

__device__ __forceinline__ u16 f2bf(float f) {
  union { float f; unsigned u; } c; c.f = f;
  unsigned r = c.u + 0x7FFFu + ((c.u >> 16) & 1u);
  return (u16)(r >> 16);
}

// ---------------- weight cast / permute / A precompute ----------------
__global__ __launch_bounds__(256) void cast_weights_k(
    const float* __restrict__ in_w, const float* __restrict__ xp_w,
    const float* __restrict__ out_w, const float* __restrict__ conv_w,
    const float* __restrict__ A_log,
    u16* __restrict__ winb, u16* __restrict__ wxpb, u16* __restrict__ woutb,
    u16* __restrict__ wconvb, float* __restrict__ Apre) {
  int i = blockIdx.x * 256 + threadIdx.x;
  if (i < 4194304) { winb[i] = f2bf(in_w[i]); return; }
  i -= 4194304;
  if (i < 262144) { wxpb[i] = f2bf(xp_w[i]); return; }
  i -= 262144;
  if (i < 2097152) { woutb[i] = f2bf(out_w[i]); return; }
  i -= 2097152;
  if (i < 524288) {
    const int m = i >> 10, r = i & 1023, kk = r >> 7, ff = r & 127;
    wconvb[i] = f2bf(conv_w[m * 1024 + ff * 8 + kk]);
    return;
  }
  i -= 524288;
  if (i < 65536) Apre[i] = -__expf(A_log[i]);
}

// ---------------- im2col for front conv (kidx = k*128 + f) ----------------
__global__ __launch_bounds__(256) void im2col_k(const float* __restrict__ x,
                                                u16* __restrict__ xc) {
  const int i = blockIdx.x * 256 + threadIdx.x;  // 2048 tokens * 1024 cols
  const int col = i & 1023, tok = i >> 10;
  const int kk = col >> 7, ff = col & 127;
  const int b = tok >> 9, to = tok & 511;
  const int t = to * 4 + kk - 7;
  const float v = (t >= 0) ? x[((size_t)b * 2048 + t) * 128 + ff] : 0.f;
  xc[i] = f2bf(v);
}

// ---------------- 1-wave 64x64 MFMA GEMM, quad-buffer, counted-vmcnt ----------------
// Partial[z][M,N] = A[M, z*Ks : (z+1)*Ks] * Bw[N, same]^T   (plain f32 store; all
// epilogues live in reduce_k).  grid.z = K-split count; mn = M*N.
__global__ __launch_bounds__(64) void gemm_k(
    const u16* __restrict__ A, int lda, const u16* __restrict__ Bw, int ldb,
    float* __restrict__ C, int ldc, int Ks, size_t mn) {
  __shared__ __align__(16) char smem[4 * 8192];  // 4 bufs x (A 4KB + B 4KB)
  const int lane = threadIdx.x;
  const int bm = blockIdx.x, bn = blockIdx.y;
  const size_t koff = (size_t)blockIdx.z * Ks;
  const int srow = lane >> 2, sslot = lane & 3;
  const int nk = Ks >> 5;
  f32x4 acc[4][4] = {};

  auto stage = [&](int buf, int kt) {
#pragma unroll
    for (int c = 0; c < 8; ++c) {
      int lrow, gr, ldx; const u16* src;
      if (c < 4) { lrow = c * 16 + srow; gr = bm * 64 + lrow; src = A; ldx = lda; }
      else { lrow = (c - 4) * 16 + srow; gr = bn * 64 + lrow; src = Bw; ldx = ldb; }
      // pre-swizzled source so LDS[row][slot] = G[row][slot ^ ((row>>1)&3)]
      const int slot = sslot ^ ((lrow >> 1) & 3);
      GLOAD16(src + (size_t)gr * ldx + koff + kt * 32 + slot * 8,
              smem + buf * 8192 + c * 1024);
    }
  };

  stage(0, 0);
  stage(1, 1);
  stage(2, 2);
  const int s = lane >> 4, r0 = lane & 15;
  for (int kt = 0; kt < nk; ++kt) {
    const int p = kt & 3;
    if (kt + 2 < nk)      asm volatile("s_waitcnt vmcnt(16)" ::: "memory");
    else if (kt + 1 < nk) asm volatile("s_waitcnt vmcnt(8)" ::: "memory");
    else                  asm volatile("s_waitcnt vmcnt(0)" ::: "memory");
    __builtin_amdgcn_sched_barrier(0);
    bf16x8 af[4], bfv[4];
#pragma unroll
    for (int i = 0; i < 4; ++i) {
      const int r = i * 16 + r0;
      af[i] = *(const bf16x8*)(smem + p * 8192 + r * 64 + ((s ^ ((r >> 1) & 3)) << 4));
      bfv[i] = *(const bf16x8*)(smem + p * 8192 + 4096 + r * 64 + ((s ^ ((r >> 1) & 3)) << 4));
    }
#pragma unroll
    for (int mi = 0; mi < 4; ++mi)
#pragma unroll
      for (int ni = 0; ni < 4; ++ni)
        acc[mi][ni] = __builtin_amdgcn_mfma_f32_16x16x32_bf16(af[mi], bfv[ni],
                                                              acc[mi][ni], 0, 0, 0);
    __builtin_amdgcn_sched_barrier(0);
    if (kt + 3 < nk) stage((kt + 3) & 3, kt + 3);
  }
  // epilogue: C/D layout col = lane&15, row = (lane>>4)*4 + reg
  const int er0 = lane & 15, eg4 = lane >> 4;
  float* Cz = C + (size_t)blockIdx.z * mn;
#pragma unroll
  for (int mi = 0; mi < 4; ++mi)
#pragma unroll
    for (int ni = 0; ni < 4; ++ni) {
      const int col = bn * 64 + ni * 16 + er0;
#pragma unroll
      for (int r = 0; r < 4; ++r) {
        const int row = bm * 64 + mi * 16 + eg4 * 4 + r;
        Cz[(size_t)row * ldc + col] = acc[mi][ni][r];
      }
    }
}

// ---------------- K-split reduce + fused epilogues ----------------
// EPI: 0 plain store | 1 +bias(col&511), exact GELU | 4 C += v
template <int NS, int EPI>
__global__ __launch_bounds__(256) void reduce_k(const float* __restrict__ P,
                                                size_t mn, float* __restrict__ C,
                                                const float* __restrict__ bias) {
  const size_t i4 = ((size_t)blockIdx.x * 256 + threadIdx.x) * 4;
  if (i4 >= mn) return;
  float4 a = *(const float4*)(P + i4);
#pragma unroll
  for (int s2 = 1; s2 < NS; ++s2) {
    const float4 b = *(const float4*)(P + (size_t)s2 * mn + i4);
    a.x += b.x; a.y += b.y; a.z += b.z; a.w += b.w;
  }
  float v[4] = {a.x, a.y, a.z, a.w};
  if constexpr (EPI == 0) {
    *(float4*)(C + i4) = a;
  } else if constexpr (EPI == 1) {
    const int col0 = (int)(i4 & 511);
#pragma unroll
    for (int j = 0; j < 4; ++j) {
      const float t = v[j] + bias[col0 + j];
      v[j] = 0.5f * t * (1.f + erff(t * 0.70710678118f));
    }
    float4 o; o.x = v[0]; o.y = v[1]; o.z = v[2]; o.w = v[3];
    *(float4*)(C + i4) = o;
  } else {
    float4 c = *(const float4*)(C + i4);
    c.x += v[0]; c.y += v[1]; c.z += v[2]; c.w += v[3];
    *(float4*)(C + i4) = c;
  }
}

// ---------------- fused dt_proj + softplus (pure VALU) ----------------
__global__ __launch_bounds__(256) void dtproj_k(const float* __restrict__ xdbl,
                                                const float* __restrict__ dtw,
                                                const float* __restrict__ dtbias,
                                                float* __restrict__ dtb) {
  __shared__ float xls[32 * 32];
  const int tid = threadIdx.x;
  const int dc = (blockIdx.x & 3) * 256;
  const int tg = (blockIdx.x >> 2) * 32;
  const int d = dc + tid;
  float4 w[8];
#pragma unroll
  for (int j = 0; j < 8; ++j) w[j] = *(const float4*)(dtw + (size_t)d * 32 + j * 4);
  for (int i = tid; i < 1024; i += 256) {
    const int t = i >> 5, r = i & 31;
    xls[i] = xdbl[(size_t)(tg + t) * 64 + r];
  }
  const float b = dtbias[d];
  __syncthreads();
  for (int t = 0; t < 32; ++t) {
    const float4* xr = (const float4*)&xls[t * 32];
    float acc = b;
#pragma unroll
    for (int j = 0; j < 8; ++j) {
      const float4 xv = xr[j];
      acc = fmaf(w[j].x, xv.x, acc); acc = fmaf(w[j].y, xv.y, acc);
      acc = fmaf(w[j].z, xv.z, acc); acc = fmaf(w[j].w, xv.w, acc);
    }
    dtb[(size_t)(tg + t) * 1024 + d] =
        fmaxf(acc, 0.f) + __logf(1.f + __expf(-fabsf(acc)));
  }
}

// ---------------- LayerNorm (DM=512) -> bf16, wave per row ----------------
__global__ __launch_bounds__(256) void ln_bf16_k(const float* __restrict__ h,
                                                 const float* __restrict__ w,
                                                 const float* __restrict__ bb,
                                                 u16* __restrict__ o) {
  const int row = blockIdx.x * 4 + (threadIdx.x >> 6);
  const int lane = threadIdx.x & 63;
  const float* p = h + (size_t)row * 512 + lane * 8;
  float4 a = *(const float4*)p;
  float4 b4 = *(const float4*)(p + 4);
  float v[8] = {a.x, a.y, a.z, a.w, b4.x, b4.y, b4.z, b4.w};
  float s = 0.f, sq = 0.f;
#pragma unroll
  for (int j = 0; j < 8; ++j) { s += v[j]; sq += v[j] * v[j]; }
  for (int off = 32; off; off >>= 1) { s += __shfl_xor(s, off); sq += __shfl_xor(sq, off); }
  const float m = s * (1.f / 512.f);
  const float rs = rsqrtf(sq * (1.f / 512.f) - m * m + 1e-5f);
  const float* wp = w + lane * 8; const float* bp = bb + lane * 8;
  float nv[8];
#pragma unroll
  for (int j = 0; j < 8; ++j) nv[j] = (v[j] - m) * rs * wp[j] + bp[j];
  uint4 uu;
  uu.x = (unsigned)f2bf(nv[0]) | ((unsigned)f2bf(nv[1]) << 16);
  uu.y = (unsigned)f2bf(nv[2]) | ((unsigned)f2bf(nv[3]) << 16);
  uu.z = (unsigned)f2bf(nv[4]) | ((unsigned)f2bf(nv[5]) << 16);
  uu.w = (unsigned)f2bf(nv[6]) | ((unsigned)f2bf(nv[7]) << 16);
  *(uint4*)(o + (size_t)row * 512 + lane * 8) = uu;
}

// ---------------- depthwise causal conv (DC=4) + SiLU ----------------
__global__ __launch_bounds__(256) void dwconv_k(const float* __restrict__ xzp,
                                                const float* __restrict__ cw,
                                                const float* __restrict__ cb,
                                                float* __restrict__ xip,
                                                u16* __restrict__ xib) {
  const int i = blockIdx.x * 256 + threadIdx.x;  // 2048*1024
  const int d = i & 1023, tok = i >> 10, t = tok & 511;
  const float* p = xzp + (size_t)tok * 2048 + d;
  float acc = cb[d];
#pragma unroll
  for (int j = 0; j < 4; ++j) {
    const int ts = t + j - 3;
    if (ts >= 0) acc = fmaf(p[(j - 3) * 2048], cw[d * 4 + j], acc);
  }
  const float v = acc / (1.f + __expf(-acc));
  xip[i] = v;
  xib[i] = f2bf(v);
}

// ---------------- chunked selective scan (16 chunks x 32 steps) ----------------
__global__ __launch_bounds__(256) void scan1_k(const float* __restrict__ dtp,
                                               const float* __restrict__ up,
                                               const float* __restrict__ xd,
                                               const float* __restrict__ Ap,
                                               float* __restrict__ hF,
                                               float* __restrict__ aP) {
  const int blk = blockIdx.x;              // b*64 + c*4 + dblk
  const int d = (blk & 3) * 256 + threadIdx.x;
  const int c = (blk >> 2) & 15, b = blk >> 6;
  float A[16], h[16], ap[16];
#pragma unroll
  for (int n = 0; n < 16; ++n) { A[n] = Ap[d * 16 + n]; h[n] = 0.f; ap[n] = 1.f; }
  const int t0 = c * 32;
  for (int t = t0; t < t0 + 32; ++t) {
    const int tok = b * 512 + t;
    const float dtv = dtp[(size_t)tok * 1024 + d];
    const float u = up[(size_t)tok * 1024 + d];
    const float s = dtv * u;
    const float* Bp = xd + (size_t)tok * 64 + 32;
#pragma unroll
    for (int n = 0; n < 16; ++n) {
      const float dA = __expf(dtv * A[n]);
      h[n] = dA * h[n] + s * Bp[n];
      ap[n] *= dA;
    }
  }
#pragma unroll
  for (int n = 0; n < 16; ++n) {
    const size_t o = ((size_t)(b * 16 + c) * 16 + n) * 1024 + d;
    hF[o] = h[n]; aP[o] = ap[n];
  }
}

__global__ __launch_bounds__(256) void scan2_k(const float* __restrict__ hF,
                                               const float* __restrict__ aP,
                                               float* __restrict__ hI) {
  // block: b(4) x n(16) x dblk(4); thread: d  -> 256 blocks
  const int bi = blockIdx.x >> 6;
  const int n = (blockIdx.x >> 2) & 15;
  const int d = (blockIdx.x & 3) * 256 + threadIdx.x;
  float h = 0.f;
  for (int c = 0; c < 16; ++c) {
    const size_t o = ((size_t)((bi * 16 + c) * 16 + n)) * 1024 + d;
    hI[o] = h;
    h = fmaf(aP[o], h, hF[o]);
  }
}

// phase 3: re-scan with correct init, fuse y2 = (y + u*D) * silu(z) -> bf16
__global__ __launch_bounds__(256) void scan3_k(const float* __restrict__ dtp,
                                               const float* __restrict__ up,
                                               const float* __restrict__ xd,
                                               const float* __restrict__ Ap,
                                               const float* __restrict__ hI,
                                               const float* __restrict__ xzp,
                                               const float* __restrict__ Dp,
                                               u16* __restrict__ y2b) {
  const int blk = blockIdx.x;
  const int d = (blk & 3) * 256 + threadIdx.x;
  const int c = (blk >> 2) & 15, b = blk >> 6;
  float A[16], h[16];
#pragma unroll
  for (int n = 0; n < 16; ++n) {
    A[n] = Ap[d * 16 + n];
    h[n] = hI[((size_t)(b * 16 + c) * 16 + n) * 1024 + d];
  }
  const float Dd = Dp[d];
  const int t0 = c * 32;
  for (int t = t0; t < t0 + 32; ++t) {
    const int tok = b * 512 + t;
    const float dtv = dtp[(size_t)tok * 1024 + d];
    const float u = up[(size_t)tok * 1024 + d];
    const float s = dtv * u;
    const float* Bp = xd + (size_t)tok * 64 + 32;
    const float* Cp = xd + (size_t)tok * 64 + 48;
    float y = 0.f;
#pragma unroll
    for (int n = 0; n < 16; ++n) {
      const float dA = __expf(dtv * A[n]);
      h[n] = dA * h[n] + s * Bp[n];
      y = fmaf(h[n], Cp[n], y);
    }
    const float z = xzp[(size_t)tok * 2048 + 1024 + d];
    const float sz = z / (1.f + __expf(-z));
    y2b[(size_t)tok * 1024 + d] = f2bf((y + u * Dd) * sz);
  }
}

// ---------------- final LN + repeat_interleave(4) upsample ----------------
__global__ __launch_bounds__(256) void final_up_k(const float* __restrict__ h,
                                                  const float* __restrict__ w,
                                                  const float* __restrict__ bb,
                                                  float* __restrict__ o) {
  const int row = blockIdx.x * 4 + (threadIdx.x >> 6);  // b*512 + t0
  const int lane = threadIdx.x & 63;
  const float* p = h + (size_t)row * 512 + lane * 8;
  float4 a = *(const float4*)p;
  float4 b4 = *(const float4*)(p + 4);
  float v[8] = {a.x, a.y, a.z, a.w, b4.x, b4.y, b4.z, b4.w};
  float s = 0.f, sq = 0.f;
#pragma unroll
  for (int j = 0; j < 8; ++j) { s += v[j]; sq += v[j] * v[j]; }
  for (int off = 32; off; off >>= 1) { s += __shfl_xor(s, off); sq += __shfl_xor(sq, off); }
  const float m = s * (1.f / 512.f);
  const float rs = rsqrtf(sq * (1.f / 512.f) - m * m + 1e-5f);
  const float* wp = w + lane * 8; const float* bp = bb + lane * 8;
  float nv[8];
#pragma unroll
  for (int j = 0; j < 8; ++j) nv[j] = (v[j] - m) * rs * wp[j] + bp[j];
  const int bi = row >> 9, t0 = row & 511;
  float4 lo; lo.x = nv[0]; lo.y = nv[1]; lo.z = nv[2]; lo.w = nv[3];
  float4 hi; hi.x = nv[4]; hi.y = nv[5]; hi.z = nv[6]; hi.w = nv[7];
  float* ob = o + ((size_t)bi * 2048 + (size_t)t0 * 4) * 512 + lane * 8;
#pragma unroll
  for (int q = 0; q < 4; ++q) {
    *(float4*)(ob + (size_t)q * 512) = lo;
    *(float4*)(ob + (size_t)q * 512 + 4) = hi;
  }
}

extern "C" void kernel_launch(void* const* d_in, const int* in_sizes, int n_in,
                              void* d_out, int out_size, void* d_ws, size_t ws_size,
                              hipStream_t stream) {
  const float* x      = (const float*)d_in[0];
  const float* conv_w = (const float*)d_in[1];
  const float* conv_b = (const float*)d_in[2];
  const float* in_w   = (const float*)d_in[3];
  const float* c1w    = (const float*)d_in[4];
  const float* c1b    = (const float*)d_in[5];
  const float* xp_w   = (const float*)d_in[6];
  const float* dt_w   = (const float*)d_in[7];
  const float* dt_b   = (const float*)d_in[8];
  const float* A_log  = (const float*)d_in[9];
  const float* D_skip = (const float*)d_in[10];
  const float* ln_w   = (const float*)d_in[11];
  const float* ln_b   = (const float*)d_in[12];
  const float* out_w  = (const float*)d_in[13];
  const float* norm_w = (const float*)d_in[14];
  const float* norm_b = (const float*)d_in[15];
  float* out = (float*)d_out;

  float* f = (float*)d_ws;
  float* h    = f; f += 1048576;   // (2048 tok, 512)
  float* xz   = f; f += 4194304;   // (2048, 2048)
  float* xi   = f; f += 2097152;   // (2048, 1024)
  float* xdbl = f; f += 131072;    // (2048, 64)
  float* dtb  = f; f += 2097152;   // (2048, 1024)
  float* Apre = f; f += 65536;     // (4, 1024, 16)
  float* hF   = f; f += 1048576;   // (4,16,16,1024)
  float* aP   = f; f += 1048576;
  float* hI   = f; f += 1048576;
  float* pp   = f; f += 4194304;   // K-split partial pool (16 MB)
  u16* ub = (u16*)f;
  u16* hnb    = ub; ub += 1048576;
  u16* xib    = ub; ub += 2097152;
  u16* y2b    = ub; ub += 2097152;
  u16* xcolb  = ub; ub += 2097152;
  u16* winb   = ub; ub += 4194304;
  u16* wxpb   = ub; ub += 262144;
  u16* woutb  = ub; ub += 2097152;
  u16* wconvb = ub; ub += 524288;

  cast_weights_k<<<27904, 256, 0, stream>>>(in_w, xp_w, out_w, conv_w, A_log,
                                            winb, wxpb, woutb, wconvb, Apre);
  im2col_k<<<8192, 256, 0, stream>>>(x, xcolb);
  // front conv as GEMM (M=2048, N=512, K=1024), K-split 4 -> 1024 blocks
  gemm_k<<<dim3(32, 8, 4), 64, 0, stream>>>(xcolb, 1024, wconvb, 1024,
                                            pp, 512, 256, (size_t)1048576);
  reduce_k<4, 1><<<1024, 256, 0, stream>>>(pp, 1048576, h, conv_b);
  for (int l = 0; l < 4; ++l) {
    ln_bf16_k<<<512, 256, 0, stream>>>(h, ln_w + l * 512, ln_b + l * 512, hnb);
    // in_proj: (2048 x 2048), K=512, 64x64 1-wave tiles -> 1024 blocks
    gemm_k<<<dim3(32, 32, 1), 64, 0, stream>>>(hnb, 512, winb + l * 1048576, 512,
                                               xz, 2048, 512, (size_t)0);
    dwconv_k<<<8192, 256, 0, stream>>>(xz, c1w + l * 4096, c1b + l * 1024, xi, xib);
    // x_proj: (2048 x 64), K-split 8 -> 256 blocks
    gemm_k<<<dim3(32, 1, 8), 64, 0, stream>>>(xib, 1024, wxpb + l * 65536,
                                              1024, pp, 64, 128, (size_t)131072);
    reduce_k<8, 0><<<128, 256, 0, stream>>>(pp, 131072, xdbl, nullptr);
    // dt_proj fused VALU kernel (K=32) + softplus
    dtproj_k<<<256, 256, 0, stream>>>(xdbl, dt_w + l * 32768, dt_b + l * 1024, dtb);
    scan1_k<<<256, 256, 0, stream>>>(dtb, xi, xdbl, Apre + l * 16384, hF, aP);
    scan2_k<<<256, 256, 0, stream>>>(hF, aP, hI);
    scan3_k<<<256, 256, 0, stream>>>(dtb, xi, xdbl, Apre + l * 16384, hI, xz,
                                     D_skip + l * 1024, y2b);
    // out_proj: (2048 x 512), K-split 4 -> 1024 blocks, reduce does h +=
    gemm_k<<<dim3(32, 8, 4), 64, 0, stream>>>(y2b, 1024, woutb + l * 524288,
                                              1024, pp, 512, 256, (size_t)1048576);
    reduce_k<4, 4><<<1024, 256, 0, stream>>>(pp, 1048576, h, nullptr);
  }
  final_up_k<<<512, 256, 0, stream>>>(h, norm_w, norm_b, out);
}